// Round 13
// baseline (285.821 us; speedup 1.0000x reference)
//
#include <hip/hip_runtime.h>

#define N_NODESC 100000
#define N_EDGESC 1600000
#define HCC 128                      // HEADS*OUT_CH
#define E_TOTC (N_EDGESC + N_NODESC) // edges + self loops (divisible by 4)
#define E_QUADS (E_TOTC / 4)         // 425000
#define SCAN_NB 391                  // ceil(N_NODES/256)
#define PROJ_NB 782                  // ceil(N_NODES/128)
#define BUILD_NB 448                 // co-resident: 2 blocks/CU (73KB LDS) x 256 CU = 512 max
#define PROJ_ROLE 320                // blocks 0..319 proj; 320..447 pos

#define FLAG_AGG 0x40000000u
#define FLAG_PRE 0x80000000u
#define VAL_MASK 0x3fffffffu

__device__ __forceinline__ float lrelu(float v) { return fmaxf(v, 0.2f * v); }
__device__ __forceinline__ unsigned short f2bf(float f) {   // RNE bf16
    unsigned u = __float_as_uint(f);
    unsigned r = ((u >> 16) & 1u) + 0x7fffu;
    return (unsigned short)((u + r) >> 16);
}

// software grid barrier: valid ONLY because all BUILD_NB blocks are co-resident.
__device__ __forceinline__ void gridbar(int* c) {
    __syncthreads();
    if (threadIdx.x == 0) {
        __threadfence();
        atomicAdd(c, 1);
        while (atomicAdd(c, 0) < BUILD_NB) { }
    }
    __syncthreads();
}

// ---- fused build kernel ----
// phase 1: blocks [0,PROJ_ROLE) augmented proj GEMM (grid-stride tiles);
//          blocks [PROJ_ROLE,BUILD_NB) atomic pos pass (4 edges/thread, dense posb).
// barrier. phase 2: blocks [0,SCAN_NB) decoupled-lookback exclusive scan -> rowptr.
// barrier. phase 3: all blocks scatter edges into dense colsrc (no atomics).
__launch_bounds__(256, 2)
__global__ void build_kernel(const float* __restrict__ x, const float* __restrict__ W,
                             const float* __restrict__ att_src, const float* __restrict__ att_dst,
                             const int* __restrict__ ei,
                             unsigned short* __restrict__ h16,
                             float* __restrict__ a_src, float* __restrict__ a_dst,
                             int* __restrict__ deg, int* __restrict__ posb,
                             unsigned* __restrict__ state, int* __restrict__ rowptr,
                             int* __restrict__ colsrc, int* __restrict__ bar) {
    __shared__ float xs[128][68];
    __shared__ float ws[64][132];
    __shared__ float us[64][16];
    __shared__ int slds[256];
    __shared__ int s_prefix;
    const int b = blockIdx.x, t = threadIdx.x;

    if (b < PROJ_ROLE) {
        // ---- proj role: stage W^T and U once (from L2-hot W), then tile loop ----
        const float4* W4 = (const float4*)W;    // 2048 float4
#pragma unroll
        for (int j = 0; j < 8; ++j) {
            int q = t + 256 * j;
            float4 v = W4[q];
            int c = q >> 4, k0 = (q & 15) * 4;
            ws[k0 + 0][c] = v.x; ws[k0 + 1][c] = v.y;
            ws[k0 + 2][c] = v.z; ws[k0 + 3][c] = v.w;
        }
#pragma unroll
        for (int j = 0; j < 4; ++j) {
            int o = t + 256 * j;
            int k = o >> 4, c = o & 15;
            const int h = c & 7;
            const float* av = (c < 8) ? att_src : att_dst;
            float s = 0.f;
#pragma unroll
            for (int jj = 0; jj < 16; ++jj) s += av[h * 16 + jj] * W[(h * 16 + jj) * 64 + k];
            us[k][c] = s;
        }

        for (int tile = b; tile < PROJ_NB; tile += PROJ_ROLE) {
            const int row0 = tile * 128;
            __syncthreads();   // ws/us ready (iter 0); xs WAR (iter >0)
#pragma unroll
            for (int j = 0; j < 8; ++j) {
                int f = (t + 256 * j) * 4;
                int r = f >> 6, k = f & 63;
                int gr = row0 + r;
                if (gr >= N_NODESC) gr = N_NODESC - 1;
                float4 v = *(const float4*)&x[(size_t)gr * 64 + k];
                *(float4*)&xs[r][k] = v;
            }
            __syncthreads();

            const int rg = t & 15;
            const int cg = t >> 4;
            float acc[8][8], acca[8];
#pragma unroll
            for (int i = 0; i < 8; ++i) {
                acca[i] = 0.f;
#pragma unroll
                for (int j = 0; j < 8; ++j) acc[i][j] = 0.f;
            }
#pragma unroll 4
            for (int k = 0; k < 64; ++k) {
                float xv[8];
#pragma unroll
                for (int i = 0; i < 8; ++i) xv[i] = xs[rg + 16 * i][k];
                float4 w0 = *(const float4*)&ws[k][4 * cg];
                float4 w1 = *(const float4*)&ws[k][64 + 4 * cg];
                float uv = us[k][cg];
#pragma unroll
                for (int i = 0; i < 8; ++i) {
                    acc[i][0] += xv[i] * w0.x; acc[i][1] += xv[i] * w0.y;
                    acc[i][2] += xv[i] * w0.z; acc[i][3] += xv[i] * w0.w;
                    acc[i][4] += xv[i] * w1.x; acc[i][5] += xv[i] * w1.y;
                    acc[i][6] += xv[i] * w1.z; acc[i][7] += xv[i] * w1.w;
                    acca[i]   += xv[i] * uv;
                }
            }
#pragma unroll
            for (int i = 0; i < 8; ++i) {
                int gr = row0 + rg + 16 * i;
                if (gr < N_NODESC) {
                    ushort4 p0, p1;
                    p0.x = f2bf(acc[i][0]); p0.y = f2bf(acc[i][1]); p0.z = f2bf(acc[i][2]); p0.w = f2bf(acc[i][3]);
                    p1.x = f2bf(acc[i][4]); p1.y = f2bf(acc[i][5]); p1.z = f2bf(acc[i][6]); p1.w = f2bf(acc[i][7]);
                    *(ushort4*)&h16[(size_t)gr * HCC + 4 * cg] = p0;
                    *(ushort4*)&h16[(size_t)gr * HCC + 64 + 4 * cg] = p1;
                    if (cg < 8) a_src[(size_t)gr * 8 + cg] = acca[i];
                    else        a_dst[(size_t)gr * 8 + cg - 8] = acca[i];
                }
            }
        }
    } else {
        // ---- pos role: 4 edges/thread quads, grid-stride; dense coalesced posb ----
        const int qid = (b - PROJ_ROLE) * 256 + t;
        const int qstride = (BUILD_NB - PROJ_ROLE) * 256;
        for (int q = qid; q < E_QUADS; q += qstride) {
            const int e0 = q * 4;
            int d[4], p[4];
            if (e0 < N_EDGESC) {       // N_EDGES divisible by 4: quad fully in range
                int4 dd = *(const int4*)&ei[N_EDGESC + e0];
                d[0] = dd.x; d[1] = dd.y; d[2] = dd.z; d[3] = dd.w;
            } else {
#pragma unroll
                for (int j = 0; j < 4; ++j) d[j] = e0 + j - N_EDGESC;
            }
#pragma unroll
            for (int j = 0; j < 4; ++j) p[j] = atomicAdd(&deg[d[j]], 1);
            *(int4*)&posb[e0] = make_int4(p[0], p[1], p[2], p[3]);
        }
    }

    gridbar(&bar[0]);

    // ---- phase 2: lookback exclusive scan -> rowptr ----
    if (b < SCAN_NB) {
        const int i = b * 256 + t;
        const int v = (i < N_NODESC) ? deg[i] : 0;
        slds[t] = v;
        __syncthreads();
        for (int off = 1; off < 256; off <<= 1) {
            int u = 0;
            if (t >= off) u = slds[t - off];
            __syncthreads();
            if (t >= off) slds[t] += u;
            __syncthreads();
        }
        const int incl = slds[t];
        const int total = slds[255];
        if (t == 0) {
            if (b == 0) {
                atomicExch(&state[0], FLAG_PRE | (unsigned)total);
                s_prefix = 0;
            } else {
                atomicExch(&state[b], FLAG_AGG | (unsigned)total);
                unsigned run = 0;
                int j = b - 1;
                while (true) {
                    unsigned s = atomicAdd(&state[j], 0u);
                    if (s & FLAG_PRE) { run += s & VAL_MASK; break; }
                    if (s & FLAG_AGG) { run += s & VAL_MASK; --j; }
                }
                atomicExch(&state[b], FLAG_PRE | ((unsigned)total + run));
                s_prefix = (int)run;
            }
        }
        __syncthreads();
        const int excl = s_prefix + incl - v;
        if (i <= N_NODESC) rowptr[i] = excl;   // i==N writes rowptr[N] = E_TOT
    }

    gridbar(&bar[1]);

    // ---- phase 3: scatter into dense colsrc (all blocks, 4 edges/thread) ----
    for (int q = b * 256 + t; q < E_QUADS; q += BUILD_NB * 256) {
        const int e0 = q * 4;
        int4 pp = *(const int4*)&posb[e0];
        int s[4], d[4], p[4] = { pp.x, pp.y, pp.z, pp.w };
        if (e0 < N_EDGESC) {
            int4 ss = *(const int4*)&ei[e0];
            int4 dd = *(const int4*)&ei[N_EDGESC + e0];
            s[0] = ss.x; s[1] = ss.y; s[2] = ss.z; s[3] = ss.w;
            d[0] = dd.x; d[1] = dd.y; d[2] = dd.z; d[3] = dd.w;
        } else {
#pragma unroll
            for (int j = 0; j < 4; ++j) { s[j] = d[j] = e0 + j - N_EDGESC; }
        }
        int r[4];
#pragma unroll
        for (int j = 0; j < 4; ++j) r[j] = rowptr[d[j]];
#pragma unroll
        for (int j = 0; j < 4; ++j) colsrc[r[j] + p[j]] = s[j];
    }
}

// ---- gather aggregation (R9 form): one wave/node, 2-deep pipeline ----
__launch_bounds__(256, 8)
__global__ void agg_csr_kernel(const int* __restrict__ rowptr, const int* __restrict__ colsrc,
                               const float* __restrict__ a_src, const float* __restrict__ a_dst,
                               const unsigned* __restrict__ h32,
                               const float* __restrict__ bias, float* __restrict__ out) {
    const int t = threadIdx.x;
    const int L = t & 63;
    const int n = blockIdx.x * 4 + (t >> 6);
    const int hd = L >> 3;
    const int eL = L & 7;

    const int beg = rowptr[n], end = rowptr[n + 1];
    const float ad = a_dst[n * 8 + hd];

    float den = 0.f;
    float acc[16];
#pragma unroll
    for (int j = 0; j < 16; ++j) acc[j] = 0.f;

    int p = beg + eL;
    bool v0 = p < end;
    bool v1 = p + 8 < end;
    int sA = v0 ? colsrc[p] : 0;
    int sB = v1 ? colsrc[p + 8] : 0;
    float avA = v0 ? a_src[sA * 8 + hd] : 0.f;

    while (v0) {
        const uint4* hp = (const uint4*)(h32 + (size_t)sA * 64 + hd * 8);
        const uint4 ha = hp[0];
        const uint4 hb = hp[1];
        const bool v2 = p + 16 < end;
        const int sC = v2 ? colsrc[p + 16] : 0;
        const float avB = v1 ? a_src[sB * 8 + hd] : 0.f;

        const float pr = __expf(lrelu(avA + ad));
        den += pr;
        acc[0]  = fmaf(pr, __uint_as_float(ha.x << 16),         acc[0]);
        acc[1]  = fmaf(pr, __uint_as_float(ha.x & 0xffff0000u), acc[1]);
        acc[2]  = fmaf(pr, __uint_as_float(ha.y << 16),         acc[2]);
        acc[3]  = fmaf(pr, __uint_as_float(ha.y & 0xffff0000u), acc[3]);
        acc[4]  = fmaf(pr, __uint_as_float(ha.z << 16),         acc[4]);
        acc[5]  = fmaf(pr, __uint_as_float(ha.z & 0xffff0000u), acc[5]);
        acc[6]  = fmaf(pr, __uint_as_float(ha.w << 16),         acc[6]);
        acc[7]  = fmaf(pr, __uint_as_float(ha.w & 0xffff0000u), acc[7]);
        acc[8]  = fmaf(pr, __uint_as_float(hb.x << 16),         acc[8]);
        acc[9]  = fmaf(pr, __uint_as_float(hb.x & 0xffff0000u), acc[9]);
        acc[10] = fmaf(pr, __uint_as_float(hb.y << 16),         acc[10]);
        acc[11] = fmaf(pr, __uint_as_float(hb.y & 0xffff0000u), acc[11]);
        acc[12] = fmaf(pr, __uint_as_float(hb.z << 16),         acc[12]);
        acc[13] = fmaf(pr, __uint_as_float(hb.z & 0xffff0000u), acc[13]);
        acc[14] = fmaf(pr, __uint_as_float(hb.w << 16),         acc[14]);
        acc[15] = fmaf(pr, __uint_as_float(hb.w & 0xffff0000u), acc[15]);

        p += 8;
        sA = sB; sB = sC; avA = avB;
        v0 = v1; v1 = v2;
    }

    den += __shfl_xor(den, 1); den += __shfl_xor(den, 2); den += __shfl_xor(den, 4);
#pragma unroll
    for (int j = 0; j < 16; ++j) {
        acc[j] += __shfl_xor(acc[j], 1);
        acc[j] += __shfl_xor(acc[j], 2);
        acc[j] += __shfl_xor(acc[j], 4);
    }
    const float inv = 1.f / (den + 1e-16f);
    float ox = acc[0], oy = acc[1];
#pragma unroll
    for (int j = 1; j < 8; ++j) {
        ox = (eL == j) ? acc[2 * j]     : ox;
        oy = (eL == j) ? acc[2 * j + 1] : oy;
    }
    const float2 b = ((const float2*)bias)[L];
    float2 o;
    o.x = fmaxf(ox * inv + b.x, 0.f);
    o.y = fmaxf(oy * inv + b.y, 0.f);
    ((float2*)out)[(size_t)n * 64 + L] = o;
}

extern "C" void kernel_launch(void* const* d_in, const int* in_sizes, int n_in,
                              void* d_out, int out_size, void* d_ws, size_t ws_size,
                              hipStream_t stream) {
    const float* x       = (const float*)d_in[0];
    const int*   ei      = (const int*)d_in[1];
    const float* W       = (const float*)d_in[2];
    const float* att_src = (const float*)d_in[3];
    const float* att_dst = (const float*)d_in[4];
    const float* bias    = (const float*)d_in[5];
    float* out = (float*)d_out;

    float* ws    = (float*)d_ws;
    unsigned short* h16 = (unsigned short*)ws;   // 12,800,000 ushorts (6.4M float slots)
    float* a_src = ws + 6400000;                 //    800,000
    float* a_dst = a_src + 800000;               //    800,000
    int* deg     = (int*)(a_dst + 800000);       //    100,000  -- memset region start
    unsigned* state = (unsigned*)(deg + 100000); //        392
    int* bar     = (int*)(state + 392);          //          8  -- memset region end
    int* rowptr  = bar + 8;                      //    100,001
    int* posb    = rowptr + 100001;              //  1,700,000
    int* colsrc  = posb + 1700000;               //  1,700,000

    hipMemsetAsync(deg, 0, (100000 + 392 + 8) * sizeof(int), stream);

    build_kernel<<<BUILD_NB, 256, 0, stream>>>(x, W, att_src, att_dst, ei,
                                               h16, a_src, a_dst,
                                               deg, posb, state, rowptr, colsrc, bar);
    agg_csr_kernel<<<N_NODESC / 4, 256, 0, stream>>>(rowptr, colsrc, a_src, a_dst,
                                                     (const unsigned*)h16, bias, out);
}